// Round 9
// baseline (203.093 us; speedup 1.0000x reference)
//
#include <hip/hip_runtime.h>

#define BN 4
#define NN 4096
#define SPLITK 2
#define LOG2E 1.44269504f
#define MFIX 36.0f

typedef __attribute__((ext_vector_type(8))) __bf16 bf16x8;
typedef __attribute__((ext_vector_type(4))) short s16x4;
typedef __attribute__((ext_vector_type(4))) float f32x4;
typedef unsigned short u16;

__device__ __forceinline__ u16 f2bf(float x) {  // manual RNE
  unsigned int u = __builtin_bit_cast(unsigned int, x);
  u = (u + 0x7fffu + ((u >> 16) & 1u)) >> 16;
  return (u16)u;
}
__device__ __forceinline__ u16 f2bfs(float x) {  // hw cvt path
  __bf16 b = (__bf16)x;
  return __builtin_bit_cast(u16, b);
}
__device__ __forceinline__ float bf2f(u16 s) {
  unsigned int u = ((unsigned int)s) << 16;
  return __builtin_bit_cast(float, u);
}

// v_mfma_f32_16x16x16_bf16. Host pass can't see amdgcn builtins (R2 lesson).
__device__ __forceinline__ f32x4 mfma16(s16x4 a, s16x4 b, f32x4 c) {
#if defined(__HIP_DEVICE_COMPILE__)
  return __builtin_amdgcn_mfma_f32_16x16x16bf16_1k(a, b, c, 0, 0, 0);
#else
  return c;
#endif
}

// async global->LDS DMA, 16B/lane: no dest VGPRs -> scheduler can't sink it.
__device__ __forceinline__ void gld16(const u16* g, u16* l) {
#if defined(__HIP_DEVICE_COMPILE__)
  __builtin_amdgcn_global_load_lds(
      (const __attribute__((address_space(1))) void*)g,
      (__attribute__((address_space(3))) void*)l, 16, 0, 0);
#else
  (void)g; (void)l;
#endif
}

#define PACK16(A, P0, P1)                                                          \
    P0.x = (unsigned)f2bf(A[0]) | ((unsigned)f2bf(A[1]) << 16);                    \
    P0.y = (unsigned)f2bf(A[2]) | ((unsigned)f2bf(A[3]) << 16);                    \
    P0.z = (unsigned)f2bf(A[4]) | ((unsigned)f2bf(A[5]) << 16);                    \
    P0.w = (unsigned)f2bf(A[6]) | ((unsigned)f2bf(A[7]) << 16);                    \
    P1.x = (unsigned)f2bf(A[8]) | ((unsigned)f2bf(A[9]) << 16);                    \
    P1.y = (unsigned)f2bf(A[10]) | ((unsigned)f2bf(A[11]) << 16);                  \
    P1.z = (unsigned)f2bf(A[12]) | ((unsigned)f2bf(A[13]) << 16);                  \
    P1.w = (unsigned)f2bf(A[14]) | ((unsigned)f2bf(A[15]) << 16);

// ---------------------------------------------------------------------------
// Kernel 1: fold Wz into Wm (bf16 Wbig + fp32 bbig).
// ---------------------------------------------------------------------------
__global__ __launch_bounds__(256) void fuse_w2_kernel(
    const float* __restrict__ Wz, const float* __restrict__ bz,
    const float* __restrict__ Wm, const float* __restrict__ bm,
    u16* __restrict__ Wbig, float* __restrict__ bbig) {
  __shared__ float wrow[128];
  __shared__ float bzs[128];
  int o = blockIdx.x;  // 192
  int t = threadIdx.x;
  if (t < 128) { wrow[t] = Wm[o * 192 + t]; bzs[t] = bz[t]; }
  __syncthreads();
  if (t < 128) {
    float s = 0.f;
#pragma unroll 4
    for (int j = 0; j < 128; ++j) s = fmaf(wrow[j], Wz[j * 128 + t], s);
    Wbig[o * 192 + t] = f2bf(s);
  } else if (t < 192) {
    Wbig[o * 192 + t] = f2bf(Wm[o * 192 + t]);
  } else if (t == 192) {
    float s = bm[o];
    for (int j = 0; j < 128; ++j) s = fmaf(wrow[j], bzs[j], s);
    bbig[o] = s;
  }
}

// ---------------------------------------------------------------------------
// Kernel 2: projections, one class per block. pid: 0=Q 1=Kh 2=Km 3=Vh 4=Vm
// 5=hT(transpose only). 16 live accs -> no spill; 1536 blocks.
// ---------------------------------------------------------------------------
__global__ __launch_bounds__(256) void proj2_kernel(
    const float* __restrict__ h, const float* __restrict__ m,
    const float* __restrict__ Wq, const float* __restrict__ bq,
    const float* __restrict__ Wk, const float* __restrict__ bk,
    const float* __restrict__ Wk2, const float* __restrict__ bk2,
    const float* __restrict__ Wv, const float* __restrict__ bv,
    const float* __restrict__ Wv2, const float* __restrict__ bv2,
    u16* __restrict__ Q, u16* __restrict__ Kh, u16* __restrict__ Km,
    u16* __restrict__ Vh, u16* __restrict__ Vm, u16* __restrict__ hT) {
  __shared__ float xs[64][65];
  int blk = blockIdx.x;  // pid*256 + b*64 + ntile
  int ntile = blk & 63, b = (blk >> 6) & 3, pid = blk >> 8;
  int n0 = ntile * 64;
  int t = threadIdx.x, nl = t & 63;
  const float* src = (pid == 2 || pid == 4) ? m : h;
  {
    int c0 = (t >> 6) * 16;
#pragma unroll
    for (int i = 0; i < 16; ++i) {
      int c = c0 + i;
      xs[c][nl] = src[((size_t)(b * 64) + c) * NN + n0 + nl];
    }
  }
  __syncthreads();
  int w = __builtin_amdgcn_readfirstlane(t >> 6);
  size_t nrow = (size_t)b * NN + n0 + nl;
  float acc[16];
  if (pid == 5) {  // hT: transpose-store only
#pragma unroll
    for (int i = 0; i < 16; ++i) acc[i] = xs[w * 16 + i][nl];
  } else {
    const float* W = pid == 0 ? Wq : pid == 1 ? Wk : pid == 2 ? Wk2 : pid == 3 ? Wv : Wv2;
    const float* bs = pid == 0 ? bq : pid == 1 ? bk : pid == 2 ? bk2 : pid == 3 ? bv : bv2;
#pragma unroll
    for (int i = 0; i < 16; ++i) acc[i] = bs[w * 16 + i];
    for (int c = 0; c < 64; ++c) {
      float x = xs[c][nl];
#pragma unroll
      for (int i = 0; i < 16; ++i) acc[i] = fmaf(W[(w * 16 + i) * 64 + c], x, acc[i]);
    }
    if (pid == 0) {
#pragma unroll
      for (int i = 0; i < 16; ++i) acc[i] *= LOG2E;  // fold softmax log2e into Q
    }
  }
  if (pid == 3 || pid == 4) {  // V: [B][64][N] c-major
    u16* dst = (pid == 3) ? Vh : Vm;
#pragma unroll
    for (int i = 0; i < 16; ++i) {
      int o = w * 16 + i;
      dst[((size_t)(b * 64) + o) * NN + n0 + nl] = f2bf(acc[i]);
    }
  } else {  // Q/Kh/Km/hT: [B][N][64] n-major, 2x16B stores
    u16* dst = pid == 0 ? Q : pid == 1 ? Kh : pid == 2 ? Km : hT;
    uint4 p0, p1;
    PACK16(acc, p0, p1);
    uint4* dp = (uint4*)(dst + nrow * 64 + w * 16);
    dp[0] = p0; dp[1] = p1;
  }
}

// ---------------------------------------------------------------------------
// Kernel 3: flash, fixed-max softmax. R8 post-mortem: bound = per-score LDS +
// issue work (every wave read the whole K/V tile; conflict counter = exactly
// 8 cyc x every b128 = structural service time). This version amortizes:
//  - 4 waves x 32 q-rows (two 16-row groups g share every K/V fragment ->
//    LDS bytes and read instructions per score HALVE; K-frag b128 count
//    should drop 8.39M -> ~4.2M in SQ_LDS_BANK_CONFLICT).
//  - 128-key tiles (TILES=16): barrier/loop/DMA overhead per score halves.
//  - LDS 64 KB/block -> 2 blocks/CU, 2 waves/SIMD, VGPR budget 256.
// ---------------------------------------------------------------------------
__global__ __launch_bounds__(256, 2) void flash8_kernel(
    const u16* __restrict__ Qg, const u16* __restrict__ Khg,
    const u16* __restrict__ Kmg, const u16* __restrict__ Vhg,
    const u16* __restrict__ Vmg, u16* __restrict__ Opart,
    float* __restrict__ Lpart) {
  __shared__ u16 Kl[2][8192];  // 16 KB per buffer: 128 rows x 8 chunks x 16B
  __shared__ u16 Vl[2][8192];  // 16 KB per buffer: 64 rows x 16 chunks x 16B
  int blk = blockIdx.x;  // combo = blk&15 -> XCD-local; qt = blk>>4 (0..31)
  int combo = blk & 15, qt = blk >> 4;
  int attn = combo & 1, b = (combo >> 1) & 3, split = combo >> 3;
  const u16* K = (attn ? Kmg : Khg) + (size_t)b * NN * 64;
  const u16* V = (attn ? Vmg : Vhg) + (size_t)b * 64 * NN;
  int t = threadIdx.x, wave = t >> 6, lane = t & 63, col = lane & 15, quad = lane >> 4;
  int row0 = qt * 128 + wave * 32;  // this wave's 32 query rows (2 groups of 16)

  bf16x8 bq[2][2];
#pragma unroll
  for (int g = 0; g < 2; ++g) {
    const u16* qp = Qg + (size_t)b * NN * 64 + (size_t)(row0 + g * 16 + col) * 64 + quad * 8;
    bq[g][0] = *(const bf16x8*)(const void*)qp;
    bq[g][1] = *(const bf16x8*)(const void*)(qp + 32);
  }

  f32x4 O[2][4];
#pragma unroll
  for (int g = 0; g < 2; ++g)
#pragma unroll
    for (int i = 0; i < 4; ++i) O[g][i] = f32x4{0.f, 0.f, 0.f, 0.f};
  f32x4 lacc[2];
  lacc[0] = f32x4{0.f, 0.f, 0.f, 0.f};
  lacc[1] = f32x4{0.f, 0.f, 0.f, 0.f};
  int sp8 = split * 8 + b * 2 + attn;

  const int kbase = split * (NN / SPLITK);
  const int TILES = NN / SPLITK / 128;  // 16

  // stage 128-key tile at K0 into buffer BUF (4 K-DMAs + 4 V-DMAs / thread)
  // K: 1024 chunks, phys = row*8 + (chunk ^ (row&7)), row 0..127
  // V: 1024 chunks, phys = c*16 + (chunk ^ (c&7)),    c   0..63
#define STAGE(BUF, K0)                                                           \
  _Pragma("unroll") for (int jj = 0; jj < 4; ++jj) {                             \
    int p = jj * 256 + t;                                                        \
    int krow_ = p >> 3;                                                          \
    int kj_ = (p & 7) ^ (krow_ & 7);                                             \
    gld16(K + (size_t)((K0) + krow_) * 64 + kj_ * 8, &Kl[BUF][p * 8]);           \
    int vrow_ = p >> 4;                                                          \
    int vj_ = (p & 15) ^ (vrow_ & 7);                                            \
    gld16(V + (size_t)vrow_ * NN + (K0) + vj_ * 8, &Vl[BUF][p * 8]);             \
  }

  STAGE(0, kbase);  // prologue

  for (int kt = 0; kt < TILES; ++kt) {
    __syncthreads();  // staging of buf kt&1 complete; prev reads of buf done
    int cur = kt & 1;
    if (kt + 1 < TILES) { STAGE(cur ^ 1, kbase + (kt + 1) * 128); }
    const u16* Kb = &Kl[cur][0];
    const u16* Vb = &Vl[cur][0];
    // St[nt][g] = K.Q^T over 8 key-subtiles; K-frags shared by both q-groups
    f32x4 St[8][2];
#pragma unroll
    for (int nt = 0; nt < 8; ++nt) {
      int row = nt * 16 + col;
      int ph0 = row * 8 + (quad ^ (col & 7));
      int ph1 = row * 8 + ((4 + quad) ^ (col & 7));
      bf16x8 a0 = *(const bf16x8*)(const void*)(Kb + ph0 * 8);
      bf16x8 a1 = *(const bf16x8*)(const void*)(Kb + ph1 * 8);
#pragma unroll
      for (int g = 0; g < 2; ++g) {
        f32x4 acc = {0.f, 0.f, 0.f, 0.f};
        acc = __builtin_amdgcn_mfma_f32_16x16x32_bf16(a0, bq[g][0], acc, 0, 0, 0);
        acc = __builtin_amdgcn_mfma_f32_16x16x32_bf16(a1, bq[g][1], acc, 0, 0, 0);
        St[nt][g] = acc;
      }
    }
    // p = exp2(St - MFIX); per-lane l accumulate; pack A-frags for PV
    s16x4 pfrag[8][2];
#pragma unroll
    for (int nt = 0; nt < 8; ++nt)
#pragma unroll
      for (int g = 0; g < 2; ++g) {
        f32x4 p;
#pragma unroll
        for (int r = 0; r < 4; ++r) p[r] = __builtin_exp2f(St[nt][g][r] - MFIX);
        lacc[g] += p;
        s16x4 pf;
#pragma unroll
        for (int r = 0; r < 4; ++r) pf[r] = (short)f2bfs(p[r]);
        pfrag[nt][g] = pf;
      }
    // O += P . V^T; V-frags shared by both q-groups
#pragma unroll
    for (int nt = 0; nt < 8; ++nt) {
      int j = nt * 2 + (quad >> 1);
#pragma unroll
      for (int ct = 0; ct < 4; ++ct) {
        int c = ct * 16 + col;
        int ph = c * 16 + (j ^ (c & 7));
        s16x4 vf = *(const s16x4*)(const void*)(Vb + ph * 8 + (quad & 1) * 4);
        O[0][ct] = mfma16(pfrag[nt][0], vf, O[0][ct]);
        O[1][ct] = mfma16(pfrag[nt][1], vf, O[1][ct]);
      }
    }
  }
#undef STAGE

  // store partials; epilogue does the /l merge
#pragma unroll
  for (int g = 0; g < 2; ++g) {
#pragma unroll
    for (int ct = 0; ct < 4; ++ct)
#pragma unroll
      for (int r = 0; r < 4; ++r) {
        size_t q = (size_t)row0 + g * 16 + quad * 4 + r;
        Opart[((size_t)sp8 * NN + q) * 64 + ct * 16 + col] = f2bfs(O[g][ct][r]);
      }
    float lsum = (lacc[g][0] + lacc[g][1]) + (lacc[g][2] + lacc[g][3]);
    lsum += __shfl_xor(lsum, 16);
    lsum += __shfl_xor(lsum, 32);
    if (lane < 16) Lpart[(size_t)sp8 * NN + row0 + g * 16 + lane] = lsum;
  }
}

// ---------------------------------------------------------------------------
// Kernel 4: fused merge + MFMA epilogue + gating.
// ---------------------------------------------------------------------------
__global__ __launch_bounds__(256) void epi3_kernel(
    const u16* __restrict__ Wb, const float* __restrict__ bb,
    const u16* __restrict__ Opart, const float* __restrict__ Lpart,
    const u16* __restrict__ hT, const float* __restrict__ mglob,
    float* __restrict__ out) {
  int blk = blockIdx.x;  // B*NN/16 = 1024
  int ng = blk * 16;
  int b = ng >> 12;
  int t = threadIdx.x, wave = t >> 6, lane = t & 63, col = lane & 15, quad = lane >> 4;
  int qb = (ng & (NN - 1)) + col;  // per-batch query row
  int s0h = b * 2, s1h = 8 + b * 2, s0m = b * 2 + 1, s1m = 9 + b * 2;
  float invLh = 1.f / (Lpart[(size_t)s0h * NN + qb] + Lpart[(size_t)s1h * NN + qb]);
  float invLm = 1.f / (Lpart[(size_t)s0m * NN + qb] + Lpart[(size_t)s1m * NN + qb]);
  size_t nrow = ((size_t)ng + col) * 64;  // for hT (global n)
  bf16x8 bfr[6];
#define MERGEF(DST, SP0, SP1, OFF, INVL)                                         \
  {                                                                              \
    const u16* p0_ = Opart + ((size_t)(SP0) * NN + qb) * 64 + (OFF);             \
    const u16* p1_ = Opart + ((size_t)(SP1) * NN + qb) * 64 + (OFF);             \
    bf16x8 a_ = *(const bf16x8*)(const void*)p0_;                                \
    bf16x8 c_ = *(const bf16x8*)(const void*)p1_;                                \
    bf16x8 r_;                                                                   \
    _Pragma("unroll") for (int i = 0; i < 8; ++i)                                \
      r_[i] = (__bf16)(((float)a_[i] + (float)c_[i]) * (INVL));                  \
    DST = r_;                                                                    \
  }
  MERGEF(bfr[0], s0h, s1h, quad * 8, invLh);
  MERGEF(bfr[1], s0h, s1h, 32 + quad * 8, invLh);
  MERGEF(bfr[2], s0m, s1m, quad * 8, invLm);
  MERGEF(bfr[3], s0m, s1m, 32 + quad * 8, invLm);
#undef MERGEF
  bfr[4] = *(const bf16x8*)(const void*)(hT + nrow + quad * 8);
  bfr[5] = *(const bf16x8*)(const void*)(hT + nrow + 32 + quad * 8);
  f32x4 acc[3];
#pragma unroll
  for (int j = 0; j < 3; ++j) {
    int mt = wave + j * 4;
#pragma unroll
    for (int r = 0; r < 4; ++r) acc[j][r] = bb[mt * 16 + quad * 4 + r];
  }
#pragma unroll
  for (int ks = 0; ks < 6; ++ks) {
#pragma unroll
    for (int j = 0; j < 3; ++j) {
      int mt = wave + j * 4;
      bf16x8 af = *(const bf16x8*)(const void*)(Wb + (size_t)(mt * 16 + col) * 192 + ks * 32 + quad * 8);
      acc[j] = __builtin_amdgcn_mfma_f32_16x16x32_bf16(af, bfr[ks], acc[j], 0, 0, 0);
    }
  }
  int nloc = (ng & (NN - 1)) + col;
#pragma unroll
  for (int r = 0; r < 4; ++r) {
    int o = wave * 16 + quad * 4 + r;
    float mo = acc[0][r], mgt = acc[1][r], mi = acc[2][r];
    float si = 1.f / (1.f + __builtin_exp2f(-mi * LOG2E));
    float tg = 1.f - 2.f / (__builtin_exp2f(2.f * LOG2E * mgt) + 1.f);
    float mv = mglob[(size_t)(b * 64 + o) * NN + nloc];
    float nm = (1.f - si) * mv + si * tg;
    float nh = nm / (1.f + __builtin_exp2f(-mo * LOG2E));
    out[(size_t)(b * 64 + o) * NN + nloc] = nh;
    out[(size_t)BN * 64 * NN + (size_t)(b * 64 + o) * NN + nloc] = nm;
  }
}

extern "C" void kernel_launch(void* const* d_in, const int* in_sizes, int n_in,
                              void* d_out, int out_size, void* d_ws, size_t ws_size,
                              hipStream_t stream) {
  const float* h = (const float*)d_in[0];
  const float* m = (const float*)d_in[1];
  const float* Wq = (const float*)d_in[2];
  const float* bq = (const float*)d_in[3];
  const float* Wk = (const float*)d_in[4];
  const float* bk = (const float*)d_in[5];
  const float* Wk2 = (const float*)d_in[6];
  const float* bk2 = (const float*)d_in[7];
  const float* Wv = (const float*)d_in[8];
  const float* bv = (const float*)d_in[9];
  const float* Wv2 = (const float*)d_in[10];
  const float* bv2 = (const float*)d_in[11];
  const float* Wz = (const float*)d_in[12];
  const float* bz = (const float*)d_in[13];
  const float* Wm = (const float*)d_in[14];
  const float* bm = (const float*)d_in[15];
  float* out = (float*)d_out;

  size_t off = 0;
  auto alloc = [&](size_t bytes) {
    void* p = (char*)d_ws + off;
    off += (bytes + 255) & ~(size_t)255;
    return p;
  };
  const size_t bn64 = (size_t)BN * NN * 64;
  u16* Q  = (u16*)alloc(bn64 * 2);
  u16* Kh = (u16*)alloc(bn64 * 2);
  u16* Km = (u16*)alloc(bn64 * 2);
  u16* Vh = (u16*)alloc(bn64 * 2);
  u16* Vm = (u16*)alloc(bn64 * 2);
  u16* hT = (u16*)alloc(bn64 * 2);
  u16* Opart = (u16*)alloc((size_t)SPLITK * 8 * NN * 64 * 2);
  float* Lpart = (float*)alloc((size_t)SPLITK * 8 * NN * 4);
  u16* Wbigbf = (u16*)alloc(192 * 192 * 2);
  float* bbig = (float*)alloc(192 * 4);
  (void)ws_size; (void)in_sizes; (void)n_in; (void)out_size;

  fuse_w2_kernel<<<192, 256, 0, stream>>>(Wz, bz, Wm, bm, Wbigbf, bbig);
  proj2_kernel<<<6 * BN * 64, 256, 0, stream>>>(h, m, Wq, bq, Wk, bk, Wk2, bk2, Wv, bv,
                                                Wv2, bv2, Q, Kh, Km, Vh, Vm, hT);
  flash8_kernel<<<512, 256, 0, stream>>>(Q, Kh, Km, Vh, Vm, Opart, Lpart);
  epi3_kernel<<<(BN * NN) / 16, 256, 0, stream>>>(Wbigbf, bbig, Opart, Lpart, hT, m, out);
}

// Round 10
// 197.020 us; speedup vs baseline: 1.0308x; 1.0308x over previous
//
#include <hip/hip_runtime.h>

#define BN 4
#define NN 4096
#define SPLITK 2
#define LOG2E 1.44269504f
#define MFIX 36.0f

typedef __attribute__((ext_vector_type(8))) __bf16 bf16x8;
typedef __attribute__((ext_vector_type(4))) short s16x4;
typedef __attribute__((ext_vector_type(4))) float f32x4;
typedef unsigned short u16;

__device__ __forceinline__ u16 f2bf(float x) {  // manual RNE
  unsigned int u = __builtin_bit_cast(unsigned int, x);
  u = (u + 0x7fffu + ((u >> 16) & 1u)) >> 16;
  return (u16)u;
}
__device__ __forceinline__ u16 f2bfs(float x) {  // hw cvt path
  __bf16 b = (__bf16)x;
  return __builtin_bit_cast(u16, b);
}
__device__ __forceinline__ float bf2f(u16 s) {
  unsigned int u = ((unsigned int)s) << 16;
  return __builtin_bit_cast(float, u);
}

// v_mfma_f32_16x16x16_bf16. Host pass can't see amdgcn builtins (R2 lesson).
__device__ __forceinline__ f32x4 mfma16(s16x4 a, s16x4 b, f32x4 c) {
#if defined(__HIP_DEVICE_COMPILE__)
  return __builtin_amdgcn_mfma_f32_16x16x16bf16_1k(a, b, c, 0, 0, 0);
#else
  return c;
#endif
}

// async global->LDS DMA, 16B/lane: no dest VGPRs -> scheduler can't sink it.
__device__ __forceinline__ void gld16(const u16* g, u16* l) {
#if defined(__HIP_DEVICE_COMPILE__)
  __builtin_amdgcn_global_load_lds(
      (const __attribute__((address_space(1))) void*)g,
      (__attribute__((address_space(3))) void*)l, 16, 0, 0);
#else
  (void)g; (void)l;
#endif
}

#define PACK16(A, P0, P1)                                                          \
    P0.x = (unsigned)f2bf(A[0]) | ((unsigned)f2bf(A[1]) << 16);                    \
    P0.y = (unsigned)f2bf(A[2]) | ((unsigned)f2bf(A[3]) << 16);                    \
    P0.z = (unsigned)f2bf(A[4]) | ((unsigned)f2bf(A[5]) << 16);                    \
    P0.w = (unsigned)f2bf(A[6]) | ((unsigned)f2bf(A[7]) << 16);                    \
    P1.x = (unsigned)f2bf(A[8]) | ((unsigned)f2bf(A[9]) << 16);                    \
    P1.y = (unsigned)f2bf(A[10]) | ((unsigned)f2bf(A[11]) << 16);                  \
    P1.z = (unsigned)f2bf(A[12]) | ((unsigned)f2bf(A[13]) << 16);                  \
    P1.w = (unsigned)f2bf(A[14]) | ((unsigned)f2bf(A[15]) << 16);

// ---------------------------------------------------------------------------
// Kernel 1: fold Wz into Wm (bf16 Wbig + fp32 bbig).
// ---------------------------------------------------------------------------
__global__ __launch_bounds__(256) void fuse_w2_kernel(
    const float* __restrict__ Wz, const float* __restrict__ bz,
    const float* __restrict__ Wm, const float* __restrict__ bm,
    u16* __restrict__ Wbig, float* __restrict__ bbig) {
  __shared__ float wrow[128];
  __shared__ float bzs[128];
  int o = blockIdx.x;  // 192
  int t = threadIdx.x;
  if (t < 128) { wrow[t] = Wm[o * 192 + t]; bzs[t] = bz[t]; }
  __syncthreads();
  if (t < 128) {
    float s = 0.f;
#pragma unroll 4
    for (int j = 0; j < 128; ++j) s = fmaf(wrow[j], Wz[j * 128 + t], s);
    Wbig[o * 192 + t] = f2bf(s);
  } else if (t < 192) {
    Wbig[o * 192 + t] = f2bf(Wm[o * 192 + t]);
  } else if (t == 192) {
    float s = bm[o];
    for (int j = 0; j < 128; ++j) s = fmaf(wrow[j], bzs[j], s);
    bbig[o] = s;
  }
}

// ---------------------------------------------------------------------------
// Kernel 2: projections, one class per block. pid: 0=Q 1=Kh 2=Km 3=Vh 4=Vm
// 5=hT(transpose only). 16 live accs -> no spill; 1536 blocks.
// ---------------------------------------------------------------------------
__global__ __launch_bounds__(256) void proj2_kernel(
    const float* __restrict__ h, const float* __restrict__ m,
    const float* __restrict__ Wq, const float* __restrict__ bq,
    const float* __restrict__ Wk, const float* __restrict__ bk,
    const float* __restrict__ Wk2, const float* __restrict__ bk2,
    const float* __restrict__ Wv, const float* __restrict__ bv,
    const float* __restrict__ Wv2, const float* __restrict__ bv2,
    u16* __restrict__ Q, u16* __restrict__ Kh, u16* __restrict__ Km,
    u16* __restrict__ Vh, u16* __restrict__ Vm, u16* __restrict__ hT) {
  __shared__ float xs[64][65];
  int blk = blockIdx.x;  // pid*256 + b*64 + ntile
  int ntile = blk & 63, b = (blk >> 6) & 3, pid = blk >> 8;
  int n0 = ntile * 64;
  int t = threadIdx.x, nl = t & 63;
  const float* src = (pid == 2 || pid == 4) ? m : h;
  {
    int c0 = (t >> 6) * 16;
#pragma unroll
    for (int i = 0; i < 16; ++i) {
      int c = c0 + i;
      xs[c][nl] = src[((size_t)(b * 64) + c) * NN + n0 + nl];
    }
  }
  __syncthreads();
  int w = __builtin_amdgcn_readfirstlane(t >> 6);
  size_t nrow = (size_t)b * NN + n0 + nl;
  float acc[16];
  if (pid == 5) {  // hT: transpose-store only
#pragma unroll
    for (int i = 0; i < 16; ++i) acc[i] = xs[w * 16 + i][nl];
  } else {
    const float* W = pid == 0 ? Wq : pid == 1 ? Wk : pid == 2 ? Wk2 : pid == 3 ? Wv : Wv2;
    const float* bs = pid == 0 ? bq : pid == 1 ? bk : pid == 2 ? bk2 : pid == 3 ? bv : bv2;
#pragma unroll
    for (int i = 0; i < 16; ++i) acc[i] = bs[w * 16 + i];
    for (int c = 0; c < 64; ++c) {
      float x = xs[c][nl];
#pragma unroll
      for (int i = 0; i < 16; ++i) acc[i] = fmaf(W[(w * 16 + i) * 64 + c], x, acc[i]);
    }
    if (pid == 0) {
#pragma unroll
      for (int i = 0; i < 16; ++i) acc[i] *= LOG2E;  // fold softmax log2e into Q
    }
  }
  if (pid == 3 || pid == 4) {  // V: [B][64][N] c-major
    u16* dst = (pid == 3) ? Vh : Vm;
#pragma unroll
    for (int i = 0; i < 16; ++i) {
      int o = w * 16 + i;
      dst[((size_t)(b * 64) + o) * NN + n0 + nl] = f2bf(acc[i]);
    }
  } else {  // Q/Kh/Km/hT: [B][N][64] n-major, 2x16B stores
    u16* dst = pid == 0 ? Q : pid == 1 ? Kh : pid == 2 ? Km : hT;
    uint4 p0, p1;
    PACK16(acc, p0, p1);
    uint4* dp = (uint4*)(dst + nrow * 64 + w * 16);
    dp[0] = p0; dp[1] = p1;
  }
}

// ---------------------------------------------------------------------------
// Kernel 3: flash, fixed-max softmax, VALU-minimized.
// R9 post-mortem: LDS work halved (conflict ctr 8.39M->4.19M exactly) but
// time flat -> bound is the dependent VALU chain (VALUBusy 57 + Mfma 27 =
// 84%). This version moves softmax work OFF the VALU pipe:
//  - QK accumulator initialized to -MFIX (MFMA adds C free) -> no v_sub.
//  - l computed by MFMA ones-trick: Lacc = mfma16(pfrag, 1.0, Lacc) ->
//    no v_add chain, no shuffles; l sums the same bf16 p that PV consumes.
// Remaining per-score VALU: exp2 + cvt/pack (irreducible).
// ---------------------------------------------------------------------------
__global__ __launch_bounds__(256, 2) void flash9_kernel(
    const u16* __restrict__ Qg, const u16* __restrict__ Khg,
    const u16* __restrict__ Kmg, const u16* __restrict__ Vhg,
    const u16* __restrict__ Vmg, u16* __restrict__ Opart,
    float* __restrict__ Lpart) {
  __shared__ u16 Kl[2][8192];  // 16 KB per buffer: 128 rows x 8 chunks x 16B
  __shared__ u16 Vl[2][8192];  // 16 KB per buffer: 64 rows x 16 chunks x 16B
  int blk = blockIdx.x;  // combo = blk&15 -> XCD-local; qt = blk>>4 (0..31)
  int combo = blk & 15, qt = blk >> 4;
  int attn = combo & 1, b = (combo >> 1) & 3, split = combo >> 3;
  const u16* K = (attn ? Kmg : Khg) + (size_t)b * NN * 64;
  const u16* V = (attn ? Vmg : Vhg) + (size_t)b * 64 * NN;
  int t = threadIdx.x, wave = t >> 6, lane = t & 63, col = lane & 15, quad = lane >> 4;
  int row0 = qt * 128 + wave * 32;  // this wave's 32 query rows (2 groups of 16)

  bf16x8 bq[2][2];
#pragma unroll
  for (int g = 0; g < 2; ++g) {
    const u16* qp = Qg + (size_t)b * NN * 64 + (size_t)(row0 + g * 16 + col) * 64 + quad * 8;
    bq[g][0] = *(const bf16x8*)(const void*)qp;
    bq[g][1] = *(const bf16x8*)(const void*)(qp + 32);
  }

  f32x4 O[2][4];
#pragma unroll
  for (int g = 0; g < 2; ++g)
#pragma unroll
    for (int i = 0; i < 4; ++i) O[g][i] = f32x4{0.f, 0.f, 0.f, 0.f};
  f32x4 Lacc[2];
  Lacc[0] = f32x4{0.f, 0.f, 0.f, 0.f};
  Lacc[1] = f32x4{0.f, 0.f, 0.f, 0.f};
  s16x4 ones;  // bf16 1.0 in all 4 slots (B-operand for the l row-sum MFMA)
#pragma unroll
  for (int i = 0; i < 4; ++i) ones[i] = (short)0x3F80;
  int sp8 = split * 8 + b * 2 + attn;

  const int kbase = split * (NN / SPLITK);
  const int TILES = NN / SPLITK / 128;  // 16

  // stage 128-key tile at K0 into buffer BUF (4 K-DMAs + 4 V-DMAs / thread)
#define STAGE(BUF, K0)                                                           \
  _Pragma("unroll") for (int jj = 0; jj < 4; ++jj) {                             \
    int p = jj * 256 + t;                                                        \
    int krow_ = p >> 3;                                                          \
    int kj_ = (p & 7) ^ (krow_ & 7);                                             \
    gld16(K + (size_t)((K0) + krow_) * 64 + kj_ * 8, &Kl[BUF][p * 8]);           \
    int vrow_ = p >> 4;                                                          \
    int vj_ = (p & 15) ^ (vrow_ & 7);                                            \
    gld16(V + (size_t)vrow_ * NN + (K0) + vj_ * 8, &Vl[BUF][p * 8]);             \
  }

  STAGE(0, kbase);  // prologue

  for (int kt = 0; kt < TILES; ++kt) {
    __syncthreads();  // staging of buf kt&1 complete; prev reads of buf done
    int cur = kt & 1;
    if (kt + 1 < TILES) { STAGE(cur ^ 1, kbase + (kt + 1) * 128); }
    const u16* Kb = &Kl[cur][0];
    const u16* Vb = &Vl[cur][0];
    // St[nt][g] = K.Q^T - MFIX (bias folded into the accumulator init)
    f32x4 St[8][2];
#pragma unroll
    for (int nt = 0; nt < 8; ++nt) {
      int row = nt * 16 + col;
      int ph0 = row * 8 + (quad ^ (col & 7));
      int ph1 = row * 8 + ((4 + quad) ^ (col & 7));
      bf16x8 a0 = *(const bf16x8*)(const void*)(Kb + ph0 * 8);
      bf16x8 a1 = *(const bf16x8*)(const void*)(Kb + ph1 * 8);
#pragma unroll
      for (int g = 0; g < 2; ++g) {
        f32x4 acc = {-MFIX, -MFIX, -MFIX, -MFIX};
        acc = __builtin_amdgcn_mfma_f32_16x16x32_bf16(a0, bq[g][0], acc, 0, 0, 0);
        acc = __builtin_amdgcn_mfma_f32_16x16x32_bf16(a1, bq[g][1], acc, 0, 0, 0);
        St[nt][g] = acc;
      }
    }
    // p = exp2(St) (no sub); pack A-frags; l via MFMA ones-trick (no v_add)
    s16x4 pfrag[8][2];
#pragma unroll
    for (int nt = 0; nt < 8; ++nt)
#pragma unroll
      for (int g = 0; g < 2; ++g) {
        s16x4 pf;
#pragma unroll
        for (int r = 0; r < 4; ++r)
          pf[r] = (short)f2bfs(__builtin_exp2f(St[nt][g][r]));
        pfrag[nt][g] = pf;
        Lacc[g] = mfma16(pf, ones, Lacc[g]);
      }
    // O += P . V^T; V-frags shared by both q-groups
#pragma unroll
    for (int nt = 0; nt < 8; ++nt) {
      int j = nt * 2 + (quad >> 1);
#pragma unroll
      for (int ct = 0; ct < 4; ++ct) {
        int c = ct * 16 + col;
        int ph = c * 16 + (j ^ (c & 7));
        s16x4 vf = *(const s16x4*)(const void*)(Vb + ph * 8 + (quad & 1) * 4);
        O[0][ct] = mfma16(pfrag[nt][0], vf, O[0][ct]);
        O[1][ct] = mfma16(pfrag[nt][1], vf, O[1][ct]);
      }
    }
  }
#undef STAGE

  // store partials; epilogue does the /l merge.
  // Lacc C-layout: lane(col,quad) reg r holds l for q=quad*4+r (all cols
  // identical) -> shuffle-free store from col 0.
#pragma unroll
  for (int g = 0; g < 2; ++g) {
#pragma unroll
    for (int ct = 0; ct < 4; ++ct)
#pragma unroll
      for (int r = 0; r < 4; ++r) {
        size_t q = (size_t)row0 + g * 16 + quad * 4 + r;
        Opart[((size_t)sp8 * NN + q) * 64 + ct * 16 + col] = f2bfs(O[g][ct][r]);
      }
    if (col == 0) {
#pragma unroll
      for (int r = 0; r < 4; ++r)
        Lpart[(size_t)sp8 * NN + row0 + g * 16 + quad * 4 + r] = Lacc[g][r];
    }
  }
}

// ---------------------------------------------------------------------------
// Kernel 4: fused merge + MFMA epilogue + gating.
// ---------------------------------------------------------------------------
__global__ __launch_bounds__(256) void epi3_kernel(
    const u16* __restrict__ Wb, const float* __restrict__ bb,
    const u16* __restrict__ Opart, const float* __restrict__ Lpart,
    const u16* __restrict__ hT, const float* __restrict__ mglob,
    float* __restrict__ out) {
  int blk = blockIdx.x;  // B*NN/16 = 1024
  int ng = blk * 16;
  int b = ng >> 12;
  int t = threadIdx.x, wave = t >> 6, lane = t & 63, col = lane & 15, quad = lane >> 4;
  int qb = (ng & (NN - 1)) + col;  // per-batch query row
  int s0h = b * 2, s1h = 8 + b * 2, s0m = b * 2 + 1, s1m = 9 + b * 2;
  float invLh = 1.f / (Lpart[(size_t)s0h * NN + qb] + Lpart[(size_t)s1h * NN + qb]);
  float invLm = 1.f / (Lpart[(size_t)s0m * NN + qb] + Lpart[(size_t)s1m * NN + qb]);
  size_t nrow = ((size_t)ng + col) * 64;  // for hT (global n)
  bf16x8 bfr[6];
#define MERGEF(DST, SP0, SP1, OFF, INVL)                                         \
  {                                                                              \
    const u16* p0_ = Opart + ((size_t)(SP0) * NN + qb) * 64 + (OFF);             \
    const u16* p1_ = Opart + ((size_t)(SP1) * NN + qb) * 64 + (OFF);             \
    bf16x8 a_ = *(const bf16x8*)(const void*)p0_;                                \
    bf16x8 c_ = *(const bf16x8*)(const void*)p1_;                                \
    bf16x8 r_;                                                                   \
    _Pragma("unroll") for (int i = 0; i < 8; ++i)                                \
      r_[i] = (__bf16)(((float)a_[i] + (float)c_[i]) * (INVL));                  \
    DST = r_;                                                                    \
  }
  MERGEF(bfr[0], s0h, s1h, quad * 8, invLh);
  MERGEF(bfr[1], s0h, s1h, 32 + quad * 8, invLh);
  MERGEF(bfr[2], s0m, s1m, quad * 8, invLm);
  MERGEF(bfr[3], s0m, s1m, 32 + quad * 8, invLm);
#undef MERGEF
  bfr[4] = *(const bf16x8*)(const void*)(hT + nrow + quad * 8);
  bfr[5] = *(const bf16x8*)(const void*)(hT + nrow + 32 + quad * 8);
  f32x4 acc[3];
#pragma unroll
  for (int j = 0; j < 3; ++j) {
    int mt = wave + j * 4;
#pragma unroll
    for (int r = 0; r < 4; ++r) acc[j][r] = bb[mt * 16 + quad * 4 + r];
  }
#pragma unroll
  for (int ks = 0; ks < 6; ++ks) {
#pragma unroll
    for (int j = 0; j < 3; ++j) {
      int mt = wave + j * 4;
      bf16x8 af = *(const bf16x8*)(const void*)(Wb + (size_t)(mt * 16 + col) * 192 + ks * 32 + quad * 8);
      acc[j] = __builtin_amdgcn_mfma_f32_16x16x32_bf16(af, bfr[ks], acc[j], 0, 0, 0);
    }
  }
  int nloc = (ng & (NN - 1)) + col;
#pragma unroll
  for (int r = 0; r < 4; ++r) {
    int o = wave * 16 + quad * 4 + r;
    float mo = acc[0][r], mgt = acc[1][r], mi = acc[2][r];
    float si = 1.f / (1.f + __builtin_exp2f(-mi * LOG2E));
    float tg = 1.f - 2.f / (__builtin_exp2f(2.f * LOG2E * mgt) + 1.f);
    float mv = mglob[(size_t)(b * 64 + o) * NN + nloc];
    float nm = (1.f - si) * mv + si * tg;
    float nh = nm / (1.f + __builtin_exp2f(-mo * LOG2E));
    out[(size_t)(b * 64 + o) * NN + nloc] = nh;
    out[(size_t)BN * 64 * NN + (size_t)(b * 64 + o) * NN + nloc] = nm;
  }
}

extern "C" void kernel_launch(void* const* d_in, const int* in_sizes, int n_in,
                              void* d_out, int out_size, void* d_ws, size_t ws_size,
                              hipStream_t stream) {
  const float* h = (const float*)d_in[0];
  const float* m = (const float*)d_in[1];
  const float* Wq = (const float*)d_in[2];
  const float* bq = (const float*)d_in[3];
  const float* Wk = (const float*)d_in[4];
  const float* bk = (const float*)d_in[5];
  const float* Wk2 = (const float*)d_in[6];
  const float* bk2 = (const float*)d_in[7];
  const float* Wv = (const float*)d_in[8];
  const float* bv = (const float*)d_in[9];
  const float* Wv2 = (const float*)d_in[10];
  const float* bv2 = (const float*)d_in[11];
  const float* Wz = (const float*)d_in[12];
  const float* bz = (const float*)d_in[13];
  const float* Wm = (const float*)d_in[14];
  const float* bm = (const float*)d_in[15];
  float* out = (float*)d_out;

  size_t off = 0;
  auto alloc = [&](size_t bytes) {
    void* p = (char*)d_ws + off;
    off += (bytes + 255) & ~(size_t)255;
    return p;
  };
  const size_t bn64 = (size_t)BN * NN * 64;
  u16* Q  = (u16*)alloc(bn64 * 2);
  u16* Kh = (u16*)alloc(bn64 * 2);
  u16* Km = (u16*)alloc(bn64 * 2);
  u16* Vh = (u16*)alloc(bn64 * 2);
  u16* Vm = (u16*)alloc(bn64 * 2);
  u16* hT = (u16*)alloc(bn64 * 2);
  u16* Opart = (u16*)alloc((size_t)SPLITK * 8 * NN * 64 * 2);
  float* Lpart = (float*)alloc((size_t)SPLITK * 8 * NN * 4);
  u16* Wbigbf = (u16*)alloc(192 * 192 * 2);
  float* bbig = (float*)alloc(192 * 4);
  (void)ws_size; (void)in_sizes; (void)n_in; (void)out_size;

  fuse_w2_kernel<<<192, 256, 0, stream>>>(Wz, bz, Wm, bm, Wbigbf, bbig);
  proj2_kernel<<<6 * BN * 64, 256, 0, stream>>>(h, m, Wq, bq, Wk, bk, Wk2, bk2, Wv, bv,
                                                Wv2, bv2, Q, Kh, Km, Vh, Vm, hT);
  flash9_kernel<<<512, 256, 0, stream>>>(Q, Kh, Km, Vh, Vm, Opart, Lpart);
  epi3_kernel<<<(BN * NN) / 16, 256, 0, stream>>>(Wbigbf, bbig, Opart, Lpart, hT, m, out);
}

// Round 11
// 175.810 us; speedup vs baseline: 1.1552x; 1.1206x over previous
//
#include <hip/hip_runtime.h>

#define BN 4
#define NN 4096
#define SPLITK 2
#define LOG2E 1.44269504f
#define MFIX 36.0f

typedef __attribute__((ext_vector_type(8))) __bf16 bf16x8;
typedef __attribute__((ext_vector_type(4))) short s16x4;
typedef __attribute__((ext_vector_type(4))) float f32x4;
typedef unsigned short u16;

__device__ __forceinline__ u16 f2bf(float x) {  // manual RNE
  unsigned int u = __builtin_bit_cast(unsigned int, x);
  u = (u + 0x7fffu + ((u >> 16) & 1u)) >> 16;
  return (u16)u;
}
__device__ __forceinline__ u16 f2bfs(float x) {  // hw cvt path
  __bf16 b = (__bf16)x;
  return __builtin_bit_cast(u16, b);
}
__device__ __forceinline__ float bf2f(u16 s) {
  unsigned int u = ((unsigned int)s) << 16;
  return __builtin_bit_cast(float, u);
}

// raw v_exp_f32 (no denormal-fixup sequence). Inputs here are in [-100, 0]:
// safely normal or flush-to-zero (p~0 contributes nothing). Guarded so a
// missing builtin falls back to libm exp2 (current behavior) instead of
// breaking the build (R2 lesson: host pass can't see amdgcn builtins).
__device__ __forceinline__ float fexp2(float x) {
#if defined(__HIP_DEVICE_COMPILE__) && __has_builtin(__builtin_amdgcn_exp2f)
  return __builtin_amdgcn_exp2f(x);
#else
  return __builtin_exp2f(x);
#endif
}

// v_mfma_f32_16x16x16_bf16.
__device__ __forceinline__ f32x4 mfma16(s16x4 a, s16x4 b, f32x4 c) {
#if defined(__HIP_DEVICE_COMPILE__)
  return __builtin_amdgcn_mfma_f32_16x16x16bf16_1k(a, b, c, 0, 0, 0);
#else
  return c;
#endif
}

// async global->LDS DMA, 16B/lane: no dest VGPRs -> scheduler can't sink it.
__device__ __forceinline__ void gld16(const u16* g, u16* l) {
#if defined(__HIP_DEVICE_COMPILE__)
  __builtin_amdgcn_global_load_lds(
      (const __attribute__((address_space(1))) void*)g,
      (__attribute__((address_space(3))) void*)l, 16, 0, 0);
#else
  (void)g; (void)l;
#endif
}

#define PACK16(A, P0, P1)                                                          \
    P0.x = (unsigned)f2bf(A[0]) | ((unsigned)f2bf(A[1]) << 16);                    \
    P0.y = (unsigned)f2bf(A[2]) | ((unsigned)f2bf(A[3]) << 16);                    \
    P0.z = (unsigned)f2bf(A[4]) | ((unsigned)f2bf(A[5]) << 16);                    \
    P0.w = (unsigned)f2bf(A[6]) | ((unsigned)f2bf(A[7]) << 16);                    \
    P1.x = (unsigned)f2bf(A[8]) | ((unsigned)f2bf(A[9]) << 16);                    \
    P1.y = (unsigned)f2bf(A[10]) | ((unsigned)f2bf(A[11]) << 16);                  \
    P1.z = (unsigned)f2bf(A[12]) | ((unsigned)f2bf(A[13]) << 16);                  \
    P1.w = (unsigned)f2bf(A[14]) | ((unsigned)f2bf(A[15]) << 16);

// ---------------------------------------------------------------------------
// Kernel 1: fold Wz into Wm (bf16 Wbig + fp32 bbig).
// ---------------------------------------------------------------------------
__global__ __launch_bounds__(256) void fuse_w2_kernel(
    const float* __restrict__ Wz, const float* __restrict__ bz,
    const float* __restrict__ Wm, const float* __restrict__ bm,
    u16* __restrict__ Wbig, float* __restrict__ bbig) {
  __shared__ float wrow[128];
  __shared__ float bzs[128];
  int o = blockIdx.x;  // 192
  int t = threadIdx.x;
  if (t < 128) { wrow[t] = Wm[o * 192 + t]; bzs[t] = bz[t]; }
  __syncthreads();
  if (t < 128) {
    float s = 0.f;
#pragma unroll 4
    for (int j = 0; j < 128; ++j) s = fmaf(wrow[j], Wz[j * 128 + t], s);
    Wbig[o * 192 + t] = f2bf(s);
  } else if (t < 192) {
    Wbig[o * 192 + t] = f2bf(Wm[o * 192 + t]);
  } else if (t == 192) {
    float s = bm[o];
    for (int j = 0; j < 128; ++j) s = fmaf(wrow[j], bzs[j], s);
    bbig[o] = s;
  }
}

// ---------------------------------------------------------------------------
// Kernel 2: projections. pid: 0=Q 1=Kh 2=Km 3=Vh 4=Vm 5=hT.
// R11: W staged to LDS (was: 1024 wave-uniform global loads per block).
// V (pids 3/4) stored in MFMA-FRAGMENT order so flash reads it with zero
// address VALU:  addr_u16(b,c,key) = b*2^18 + (key>>4)*1024 + (c>>4)*256
//                                  + ((key>>2)&3)*64 + (c&15)*4 + (key&3)
// ---------------------------------------------------------------------------
__global__ __launch_bounds__(256) void proj3_kernel(
    const float* __restrict__ h, const float* __restrict__ m,
    const float* __restrict__ Wq, const float* __restrict__ bq,
    const float* __restrict__ Wk, const float* __restrict__ bk,
    const float* __restrict__ Wk2, const float* __restrict__ bk2,
    const float* __restrict__ Wv, const float* __restrict__ bv,
    const float* __restrict__ Wv2, const float* __restrict__ bv2,
    u16* __restrict__ Q, u16* __restrict__ Kh, u16* __restrict__ Km,
    u16* __restrict__ Vh, u16* __restrict__ Vm, u16* __restrict__ hT) {
  __shared__ float xs[64][65];
  __shared__ float Wl[4096];
  int blk = blockIdx.x;  // pid*256 + b*64 + ntile
  int ntile = blk & 63, b = (blk >> 6) & 3, pid = blk >> 8;
  int n0 = ntile * 64;
  int t = threadIdx.x, nl = t & 63;
  const float* src = (pid == 2 || pid == 4) ? m : h;
  {
    int c0 = (t >> 6) * 16;
#pragma unroll
    for (int i = 0; i < 16; ++i) {
      int c = c0 + i;
      xs[c][nl] = src[((size_t)(b * 64) + c) * NN + n0 + nl];
    }
  }
  if (pid < 5) {
    const float* W = pid == 0 ? Wq : pid == 1 ? Wk : pid == 2 ? Wk2 : pid == 3 ? Wv : Wv2;
#pragma unroll
    for (int i = 0; i < 16; ++i) Wl[i * 256 + t] = W[i * 256 + t];
  }
  __syncthreads();
  int w = __builtin_amdgcn_readfirstlane(t >> 6);
  size_t nrow = (size_t)b * NN + n0 + nl;
  float acc[16];
  if (pid == 5) {  // hT: transpose-store only
#pragma unroll
    for (int i = 0; i < 16; ++i) acc[i] = xs[w * 16 + i][nl];
  } else {
    const float* bs = pid == 0 ? bq : pid == 1 ? bk : pid == 2 ? bk2 : pid == 3 ? bv : bv2;
#pragma unroll
    for (int i = 0; i < 16; ++i) acc[i] = bs[w * 16 + i];
    for (int c = 0; c < 64; ++c) {
      float x = xs[c][nl];
#pragma unroll
      for (int i = 0; i < 16; ++i) acc[i] = fmaf(Wl[(w * 16 + i) * 64 + c], x, acc[i]);
    }
    if (pid == 0) {
#pragma unroll
      for (int i = 0; i < 16; ++i) acc[i] *= LOG2E;  // fold softmax log2e into Q
    }
  }
  if (pid == 3 || pid == 4) {  // V: fragment-order layout (see header comment)
    u16* dst = (pid == 3) ? Vh : Vm;
    int key = n0 + nl;
    size_t base = ((size_t)b << 18) + (size_t)(key >> 4) * 1024 + w * 256 +
                  ((key >> 2) & 3) * 64 + (key & 3);
#pragma unroll
    for (int i = 0; i < 16; ++i) dst[base + i * 4] = f2bf(acc[i]);
  } else {  // Q/Kh/Km/hT: [B][N][64] n-major, 2x16B stores
    u16* dst = pid == 0 ? Q : pid == 1 ? Kh : pid == 2 ? Km : hT;
    uint4 p0, p1;
    PACK16(acc, p0, p1);
    uint4* dp = (uint4*)(dst + nrow * 64 + w * 16);
    dp[0] = p0; dp[1] = p1;
  }
}

// ---------------------------------------------------------------------------
// Kernel 3: flash, fixed-max softmax, VALU-stripped.
// R10 post-mortem: ~1900 unaccounted VALU cyc/wave-tile = exp2 denormal
// fixup (~600) + 64 acc-init movs (~130) + V-read XOR addressing (~150) +
// misc. This version:
//  - raw v_exp_f32 (fexp2), no fixup.
//  - QK C-operand = shared const minit vector (MFMA C!=D; zero movs).
//  - V staged/read in fragment order: staging is a contiguous 16KB copy;
//    reads are lane-base + immediate offset (0 VALU, sequential banks).
// ---------------------------------------------------------------------------
__global__ __launch_bounds__(256, 2) void flash10_kernel(
    const u16* __restrict__ Qg, const u16* __restrict__ Khg,
    const u16* __restrict__ Kmg, const u16* __restrict__ Vhg,
    const u16* __restrict__ Vmg, u16* __restrict__ Opart,
    float* __restrict__ Lpart) {
  __shared__ u16 Kl[2][8192];  // 16 KB per buffer: 128 rows x 8 chunks x 16B
  __shared__ u16 Vl[2][8192];  // 16 KB per buffer: fragment order
  int blk = blockIdx.x;  // combo = blk&15 -> XCD-local; qt = blk>>4 (0..31)
  int combo = blk & 15, qt = blk >> 4;
  int attn = combo & 1, b = (combo >> 1) & 3, split = combo >> 3;
  const u16* K = (attn ? Kmg : Khg) + (size_t)b * NN * 64;
  const u16* V = (attn ? Vmg : Vhg) + ((size_t)b << 18);  // frag-order base
  int t = threadIdx.x, wave = t >> 6, lane = t & 63, col = lane & 15, quad = lane >> 4;
  int row0 = qt * 128 + wave * 32;  // this wave's 32 query rows (2 groups of 16)

  bf16x8 bq[2][2];
#pragma unroll
  for (int g = 0; g < 2; ++g) {
    const u16* qp = Qg + (size_t)b * NN * 64 + (size_t)(row0 + g * 16 + col) * 64 + quad * 8;
    bq[g][0] = *(const bf16x8*)(const void*)qp;
    bq[g][1] = *(const bf16x8*)(const void*)(qp + 32);
  }

  f32x4 O[2][4];
#pragma unroll
  for (int g = 0; g < 2; ++g)
#pragma unroll
    for (int i = 0; i < 4; ++i) O[g][i] = f32x4{0.f, 0.f, 0.f, 0.f};
  f32x4 Lacc[2];
  Lacc[0] = f32x4{0.f, 0.f, 0.f, 0.f};
  Lacc[1] = f32x4{0.f, 0.f, 0.f, 0.f};
  const f32x4 minit = {-MFIX, -MFIX, -MFIX, -MFIX};  // shared C-operand
  s16x4 ones;  // bf16 1.0 x4 (B-operand for the l row-sum MFMA)
#pragma unroll
  for (int i = 0; i < 4; ++i) ones[i] = (short)0x3F80;
  int sp8 = split * 8 + b * 2 + attn;

  const int kbase = split * (NN / SPLITK);
  const int TILES = NN / SPLITK / 128;  // 16

  // stage 128-key tile at K0 into buffer BUF (4 K-DMAs + 4 V-DMAs / thread)
  // K: XOR-swizzled rows (as before). V: straight contiguous copy (frag order
  // in global already); tile base = V + K0*64 u16, 8192 u16 = 16 KB.
#define STAGE(BUF, K0)                                                           \
  _Pragma("unroll") for (int jj = 0; jj < 4; ++jj) {                             \
    int p = jj * 256 + t;                                                        \
    int krow_ = p >> 3;                                                          \
    int kj_ = (p & 7) ^ (krow_ & 7);                                             \
    gld16(K + (size_t)((K0) + krow_) * 64 + kj_ * 8, &Kl[BUF][p * 8]);           \
    gld16(V + (size_t)(K0) * 64 + p * 8, &Vl[BUF][p * 8]);                       \
  }

  STAGE(0, kbase);  // prologue

  for (int kt = 0; kt < TILES; ++kt) {
    __syncthreads();  // staging of buf kt&1 complete; prev reads of buf done
    int cur = kt & 1;
    if (kt + 1 < TILES) { STAGE(cur ^ 1, kbase + (kt + 1) * 128); }
    const u16* Kb = &Kl[cur][0];
    const u16* Vb = &Vl[cur][0];
    // St[nt][g] = K.Q^T - MFIX (bias via shared const C; no per-MFMA movs)
    f32x4 St[8][2];
#pragma unroll
    for (int nt = 0; nt < 8; ++nt) {
      int row = nt * 16 + col;
      int ph0 = row * 8 + (quad ^ (col & 7));
      int ph1 = row * 8 + ((4 + quad) ^ (col & 7));
      bf16x8 a0 = *(const bf16x8*)(const void*)(Kb + ph0 * 8);
      bf16x8 a1 = *(const bf16x8*)(const void*)(Kb + ph1 * 8);
#pragma unroll
      for (int g = 0; g < 2; ++g) {
        f32x4 acc = __builtin_amdgcn_mfma_f32_16x16x32_bf16(a0, bq[g][0], minit, 0, 0, 0);
        acc = __builtin_amdgcn_mfma_f32_16x16x32_bf16(a1, bq[g][1], acc, 0, 0, 0);
        St[nt][g] = acc;
      }
    }
    // p = exp2(St) raw; pack A-frags; l via MFMA ones-trick
    s16x4 pfrag[8][2];
#pragma unroll
    for (int nt = 0; nt < 8; ++nt)
#pragma unroll
      for (int g = 0; g < 2; ++g) {
        s16x4 pf;
#pragma unroll
        for (int r = 0; r < 4; ++r) pf[r] = (short)f2bfs(fexp2(St[nt][g][r]));
        pfrag[nt][g] = pf;
        Lacc[g] = mfma16(pf, ones, Lacc[g]);
      }
    // O += P . V^T; V-frags at lane-base + immediate offsets (0 VALU)
    const u16* vbase = Vb + quad * 64 + col * 4;
#pragma unroll
    for (int nt = 0; nt < 8; ++nt) {
#pragma unroll
      for (int ct = 0; ct < 4; ++ct) {
        s16x4 vf = *(const s16x4*)(const void*)(vbase + nt * 1024 + ct * 256);
        O[0][ct] = mfma16(pfrag[nt][0], vf, O[0][ct]);
        O[1][ct] = mfma16(pfrag[nt][1], vf, O[1][ct]);
      }
    }
  }
#undef STAGE

  // store partials; epilogue does the /l merge. Lacc C-layout: reg r holds l
  // for q=quad*4+r (identical across cols) -> shuffle-free store from col 0.
#pragma unroll
  for (int g = 0; g < 2; ++g) {
#pragma unroll
    for (int ct = 0; ct < 4; ++ct)
#pragma unroll
      for (int r = 0; r < 4; ++r) {
        size_t q = (size_t)row0 + g * 16 + quad * 4 + r;
        Opart[((size_t)sp8 * NN + q) * 64 + ct * 16 + col] = f2bfs(O[g][ct][r]);
      }
    if (col == 0) {
#pragma unroll
      for (int r = 0; r < 4; ++r)
        Lpart[(size_t)sp8 * NN + row0 + g * 16 + quad * 4 + r] = Lacc[g][r];
    }
  }
}

// ---------------------------------------------------------------------------
// Kernel 4: fused merge + MFMA epilogue + gating.
// ---------------------------------------------------------------------------
__global__ __launch_bounds__(256) void epi3_kernel(
    const u16* __restrict__ Wb, const float* __restrict__ bb,
    const u16* __restrict__ Opart, const float* __restrict__ Lpart,
    const u16* __restrict__ hT, const float* __restrict__ mglob,
    float* __restrict__ out) {
  int blk = blockIdx.x;  // B*NN/16 = 1024
  int ng = blk * 16;
  int b = ng >> 12;
  int t = threadIdx.x, wave = t >> 6, lane = t & 63, col = lane & 15, quad = lane >> 4;
  int qb = (ng & (NN - 1)) + col;  // per-batch query row
  int s0h = b * 2, s1h = 8 + b * 2, s0m = b * 2 + 1, s1m = 9 + b * 2;
  float invLh = 1.f / (Lpart[(size_t)s0h * NN + qb] + Lpart[(size_t)s1h * NN + qb]);
  float invLm = 1.f / (Lpart[(size_t)s0m * NN + qb] + Lpart[(size_t)s1m * NN + qb]);
  size_t nrow = ((size_t)ng + col) * 64;  // for hT (global n)
  bf16x8 bfr[6];
#define MERGEF(DST, SP0, SP1, OFF, INVL)                                         \
  {                                                                              \
    const u16* p0_ = Opart + ((size_t)(SP0) * NN + qb) * 64 + (OFF);             \
    const u16* p1_ = Opart + ((size_t)(SP1) * NN + qb) * 64 + (OFF);             \
    bf16x8 a_ = *(const bf16x8*)(const void*)p0_;                                \
    bf16x8 c_ = *(const bf16x8*)(const void*)p1_;                                \
    bf16x8 r_;                                                                   \
    _Pragma("unroll") for (int i = 0; i < 8; ++i)                                \
      r_[i] = (__bf16)(((float)a_[i] + (float)c_[i]) * (INVL));                  \
    DST = r_;                                                                    \
  }
  MERGEF(bfr[0], s0h, s1h, quad * 8, invLh);
  MERGEF(bfr[1], s0h, s1h, 32 + quad * 8, invLh);
  MERGEF(bfr[2], s0m, s1m, quad * 8, invLm);
  MERGEF(bfr[3], s0m, s1m, 32 + quad * 8, invLm);
#undef MERGEF
  bfr[4] = *(const bf16x8*)(const void*)(hT + nrow + quad * 8);
  bfr[5] = *(const bf16x8*)(const void*)(hT + nrow + 32 + quad * 8);
  f32x4 acc[3];
#pragma unroll
  for (int j = 0; j < 3; ++j) {
    int mt = wave + j * 4;
#pragma unroll
    for (int r = 0; r < 4; ++r) acc[j][r] = bb[mt * 16 + quad * 4 + r];
  }
#pragma unroll
  for (int ks = 0; ks < 6; ++ks) {
#pragma unroll
    for (int j = 0; j < 3; ++j) {
      int mt = wave + j * 4;
      bf16x8 af = *(const bf16x8*)(const void*)(Wb + (size_t)(mt * 16 + col) * 192 + ks * 32 + quad * 8);
      acc[j] = __builtin_amdgcn_mfma_f32_16x16x32_bf16(af, bfr[ks], acc[j], 0, 0, 0);
    }
  }
  int nloc = (ng & (NN - 1)) + col;
#pragma unroll
  for (int r = 0; r < 4; ++r) {
    int o = wave * 16 + quad * 4 + r;
    float mo = acc[0][r], mgt = acc[1][r], mi = acc[2][r];
    float si = 1.f / (1.f + fexp2(-mi * LOG2E));
    float tg = 1.f - 2.f / (fexp2(2.f * LOG2E * mgt) + 1.f);
    float mv = mglob[(size_t)(b * 64 + o) * NN + nloc];
    float nm = (1.f - si) * mv + si * tg;
    float nh = nm / (1.f + fexp2(-mo * LOG2E));
    out[(size_t)(b * 64 + o) * NN + nloc] = nh;
    out[(size_t)BN * 64 * NN + (size_t)(b * 64 + o) * NN + nloc] = nm;
  }
}

extern "C" void kernel_launch(void* const* d_in, const int* in_sizes, int n_in,
                              void* d_out, int out_size, void* d_ws, size_t ws_size,
                              hipStream_t stream) {
  const float* h = (const float*)d_in[0];
  const float* m = (const float*)d_in[1];
  const float* Wq = (const float*)d_in[2];
  const float* bq = (const float*)d_in[3];
  const float* Wk = (const float*)d_in[4];
  const float* bk = (const float*)d_in[5];
  const float* Wk2 = (const float*)d_in[6];
  const float* bk2 = (const float*)d_in[7];
  const float* Wv = (const float*)d_in[8];
  const float* bv = (const float*)d_in[9];
  const float* Wv2 = (const float*)d_in[10];
  const float* bv2 = (const float*)d_in[11];
  const float* Wz = (const float*)d_in[12];
  const float* bz = (const float*)d_in[13];
  const float* Wm = (const float*)d_in[14];
  const float* bm = (const float*)d_in[15];
  float* out = (float*)d_out;

  size_t off = 0;
  auto alloc = [&](size_t bytes) {
    void* p = (char*)d_ws + off;
    off += (bytes + 255) & ~(size_t)255;
    return p;
  };
  const size_t bn64 = (size_t)BN * NN * 64;
  u16* Q  = (u16*)alloc(bn64 * 2);
  u16* Kh = (u16*)alloc(bn64 * 2);
  u16* Km = (u16*)alloc(bn64 * 2);
  u16* Vh = (u16*)alloc(bn64 * 2);
  u16* Vm = (u16*)alloc(bn64 * 2);
  u16* hT = (u16*)alloc(bn64 * 2);
  u16* Opart = (u16*)alloc((size_t)SPLITK * 8 * NN * 64 * 2);
  float* Lpart = (float*)alloc((size_t)SPLITK * 8 * NN * 4);
  u16* Wbigbf = (u16*)alloc(192 * 192 * 2);
  float* bbig = (float*)alloc(192 * 4);
  (void)ws_size; (void)in_sizes; (void)n_in; (void)out_size;

  fuse_w2_kernel<<<192, 256, 0, stream>>>(Wz, bz, Wm, bm, Wbigbf, bbig);
  proj3_kernel<<<6 * BN * 64, 256, 0, stream>>>(h, m, Wq, bq, Wk, bk, Wk2, bk2, Wv, bv,
                                                Wv2, bv2, Q, Kh, Km, Vh, Vm, hT);
  flash10_kernel<<<512, 256, 0, stream>>>(Q, Kh, Km, Vh, Vm, Opart, Lpart);
  epi3_kernel<<<(BN * NN) / 16, 256, 0, stream>>>(Wbigbf, bbig, Opart, Lpart, hT, m, out);
}